// Round 12
// baseline (367.319 us; speedup 1.0000x reference)
//
#include <hip/hip_runtime.h>
#include <hip/hip_bf16.h>

// GCN 3-layer. Linearity: segsum(h[src]) @ W == segsum((h@W)[src]).
// R12: FEATURE-CHUNKED gather buffers. X split column-wise into 8 chunks of
//      16 features (32B/row, 3.2MB/chunk), stored chunk-major [8][N][16]bf16.
//      agg blocks with blockIdx%8==c process only chunk c -> round-robin
//      block->XCD dispatch pins chunk c to one XCD; 3.2MB fits its 4MB L2 ->
//      gathers become L2 hits (R9-R11 showed 178MB = 8 XCDs refilling the
//      whole 25.6MB table; that compulsory fill was the 58us agg floor).
//      Same instruction count (8 passes x 1/8 features). Math bit-identical.
//      R11's mm0-fusion/inline-transpose/SCAT_TILE reverted (neutral-negative).
// Pipeline:
//   prep_w; bin_count -> bin_scan -> bin_scatter -> csr_build
//   bufA = features @ Wt0        (mm128_mfma<f32>, chunked C)
//   bufB = relu(agg(bufA)+b0)    (agg128_chunk x8 feature-chunks)
//   bufA = bufB @ Wt1            (mm128_mfma<bf16>, chunked A and C)
//   bufB = relu(agg(bufA)+b1)    (agg128_chunk)
//   bufC = bufB @ W2t            (mm40_mfma, chunked A, 64-padded chunked C)
//   out  = agg40_chunk(bufC)+b2  (chunks 0..4 = 40 features)

#define FEAT 128
#define BIN_SHIFT 8
#define MAX_BINS 512
#define SCAT_TILE 8192

typedef __attribute__((ext_vector_type(8))) short bf16x8_t;
typedef __attribute__((ext_vector_type(4))) float f32x4_t;

// ---------------- helpers ----------------

__device__ __forceinline__ void bf16x8_add(float* a, uint4 v) {
    a[0] += __uint_as_float(v.x << 16);
    a[1] += __uint_as_float(v.x & 0xffff0000u);
    a[2] += __uint_as_float(v.y << 16);
    a[3] += __uint_as_float(v.y & 0xffff0000u);
    a[4] += __uint_as_float(v.z << 16);
    a[5] += __uint_as_float(v.z & 0xffff0000u);
    a[6] += __uint_as_float(v.w << 16);
    a[7] += __uint_as_float(v.w & 0xffff0000u);
}

__device__ __forceinline__ unsigned pack_bf16(float a, float b) {
    union { __hip_bfloat162 h; unsigned u; } c;
    c.h.x = __float2bfloat16(a);
    c.h.y = __float2bfloat16(b);
    return c.u;
}

__device__ __forceinline__ unsigned short f2bf(float x) {
    union { __hip_bfloat16 h; unsigned short s; } c;
    c.h = __float2bfloat16(x);
    return c.s;
}

// ---------------- CSR build ----------------

__global__ __launch_bounds__(256) void bin_count(const int* __restrict__ dst,
                                                 int* __restrict__ bin_counts,
                                                 int n_edges, int nb) {
    __shared__ int hist[MAX_BINS];
    const int t = threadIdx.x;
    for (int i = t; i < nb; i += 256) hist[i] = 0;
    __syncthreads();
    const int n4 = n_edges >> 2;
    for (int i = blockIdx.x * 256 + t; i < n4; i += gridDim.x * 256) {
        int4 d = ((const int4*)dst)[i];
        atomicAdd(&hist[d.x >> BIN_SHIFT], 1);
        atomicAdd(&hist[d.y >> BIN_SHIFT], 1);
        atomicAdd(&hist[d.z >> BIN_SHIFT], 1);
        atomicAdd(&hist[d.w >> BIN_SHIFT], 1);
    }
    if (blockIdx.x == 0 && t < (n_edges & 3))
        atomicAdd(&hist[dst[n4 * 4 + t] >> BIN_SHIFT], 1);
    __syncthreads();
    for (int i = t; i < nb; i += 256) {
        int h = hist[i];
        if (h) atomicAdd(&bin_counts[i], h);
    }
}

__global__ __launch_bounds__(512) void bin_scan(const int* __restrict__ bin_counts,
                                                int* __restrict__ bin_offsets,
                                                int* __restrict__ bin_cursor,
                                                int* __restrict__ offsets,
                                                int nb, int n_nodes, int n_edges) {
    __shared__ int sc[512];
    const int t = threadIdx.x;
    const int v = (t < nb) ? bin_counts[t] : 0;
    sc[t] = v;
    __syncthreads();
    for (int off = 1; off < 512; off <<= 1) {
        int u = (t >= off) ? sc[t - off] : 0;
        __syncthreads();
        sc[t] += u;
        __syncthreads();
    }
    if (t <= nb) {
        int e = (t < nb) ? (sc[t] - v) : n_edges;
        bin_offsets[t] = e;
        if (t < nb) bin_cursor[t] = e;
    }
    if (t == 0) offsets[n_nodes] = n_edges;
}

__global__ __launch_bounds__(256) void bin_scatter(const int* __restrict__ src,
                                                   const int* __restrict__ dst,
                                                   int* __restrict__ bin_cursor,
                                                   int* __restrict__ ebuf,
                                                   int n_edges, int nb) {
    __shared__ int hist[MAX_BINS];
    __shared__ int cur[MAX_BINS];
    const int t = threadIdx.x;
    const int lo = blockIdx.x * SCAT_TILE;
    const int hi = min(lo + SCAT_TILE, n_edges);
    for (int i = t; i < nb; i += 256) hist[i] = 0;
    __syncthreads();
    for (int i = lo + t; i < hi; i += 256) atomicAdd(&hist[dst[i] >> BIN_SHIFT], 1);
    __syncthreads();
    for (int i = t; i < nb; i += 256) {
        int h = hist[i];
        cur[i] = h ? atomicAdd(&bin_cursor[i], h) : 0;
    }
    __syncthreads();
    for (int i = lo + t; i < hi; i += 256) {
        int d = dst[i];
        int b = d >> BIN_SHIFT;
        int pos = atomicAdd(&cur[b], 1);
        ebuf[pos] = ((d & 255) << 24) | src[i];
    }
}

__global__ __launch_bounds__(256) void csr_build(const int* __restrict__ ebuf,
                                                 const int* __restrict__ bin_offsets,
                                                 int* __restrict__ offsets,
                                                 int* __restrict__ csr,
                                                 int n_nodes) {
    __shared__ int cnt[256];
    __shared__ int sc[256];
    __shared__ int cur[256];
    const int b = blockIdx.x;
    const int t = threadIdx.x;
    const int lo = bin_offsets[b];
    const int hi = bin_offsets[b + 1];
    cnt[t] = 0;
    __syncthreads();
    for (int e = lo + t; e < hi; e += 256)
        atomicAdd(&cnt[((unsigned)ebuf[e]) >> 24], 1);
    __syncthreads();
    const int x = cnt[t];
    sc[t] = x;
    __syncthreads();
    for (int off = 1; off < 256; off <<= 1) {
        int u = (t >= off) ? sc[t - off] : 0;
        __syncthreads();
        sc[t] += u;
        __syncthreads();
    }
    const int start = lo + sc[t] - x;
    cur[t] = start;
    const int node = (b << BIN_SHIFT) + t;
    if (node < n_nodes) offsets[node] = start;
    __syncthreads();
    for (int e = lo + t; e < hi; e += 256) {
        int p = ebuf[e];
        int dl = ((unsigned)p) >> 24;
        int pos = atomicAdd(&cur[dl], 1);
        csr[pos] = p & 0x00FFFFFF;
    }
}

// -------- prep_w: Wt0/Wt1[n][k] bf16 from W0/W1[k][n] f32; W2t[48][128] bf16 ----

__global__ __launch_bounds__(256) void prep_w(const float* __restrict__ W0,
                                              const float* __restrict__ W1,
                                              const float* __restrict__ W2,
                                              unsigned short* __restrict__ Wt0,
                                              unsigned short* __restrict__ Wt1,
                                              unsigned short* __restrict__ W2t) {
    int i = blockIdx.x * 256 + threadIdx.x;  // 0..38911
    if (i < 32768) {
        const float* W = (i < 16384) ? W0 : W1;
        unsigned short* Wt = (i < 16384) ? Wt0 : Wt1;
        int ii = i & 16383;
        int k = ii >> 7, nn = ii & 127;
        Wt[nn * 128 + k] = f2bf(W[ii]);
    } else if (i < 32768 + 48 * 128) {
        int ii = i - 32768;
        int nn = ii >> 7, k = ii & 127;
        W2t[ii] = (nn < 40) ? f2bf(W2[k * 40 + nn]) : (unsigned short)0;
    }
}

// ------- agg128_chunk: one 16-feature chunk per block; chunk = blockIdx%8 ------
// Layout: X,Y chunk-major [8][N][8 uints] (32B rows). 2 lanes/node (uint4 each),
// 128 nodes per 256-thread block. Chunk table 3.2MB -> L2-resident per XCD.

__global__ __launch_bounds__(256) void agg128_chunk(const unsigned* __restrict__ X,
                                                    const int* __restrict__ offsets,
                                                    const int* __restrict__ csr_src,
                                                    const float* __restrict__ bias,
                                                    unsigned* __restrict__ Yb,
                                                    int n, size_t cN) {
    const int t = threadIdx.x;
    const int chunk = blockIdx.x & 7;
    const int node = (blockIdx.x >> 3) * 128 + (t >> 1);
    const int L = t & 1;
    if (node >= n) return;
    const unsigned* Xc = X + (size_t)chunk * cN;
    const int e0 = offsets[node];
    const int e1 = offsets[node + 1];
    float acc[8] = {0.f, 0.f, 0.f, 0.f, 0.f, 0.f, 0.f, 0.f};
    int e = e0;
    for (; e + 3 < e1; e += 4) {
        int s0 = csr_src[e];
        int s1 = csr_src[e + 1];
        int s2 = csr_src[e + 2];
        int s3 = csr_src[e + 3];
        uint4 v0 = *(const uint4*)(Xc + (size_t)s0 * 8 + L * 4);
        uint4 v1 = *(const uint4*)(Xc + (size_t)s1 * 8 + L * 4);
        uint4 v2 = *(const uint4*)(Xc + (size_t)s2 * 8 + L * 4);
        uint4 v3 = *(const uint4*)(Xc + (size_t)s3 * 8 + L * 4);
        bf16x8_add(acc, v0);
        bf16x8_add(acc, v1);
        bf16x8_add(acc, v2);
        bf16x8_add(acc, v3);
    }
    for (; e < e1; ++e) {
        int s0 = csr_src[e];
        uint4 v0 = *(const uint4*)(Xc + (size_t)s0 * 8 + L * 4);
        bf16x8_add(acc, v0);
    }
    const float* bp = bias + chunk * 16 + L * 8;
    float4 b0 = *(const float4*)bp;
    float4 b1 = *(const float4*)(bp + 4);
    acc[0] = fmaxf(acc[0] + b0.x, 0.f);
    acc[1] = fmaxf(acc[1] + b0.y, 0.f);
    acc[2] = fmaxf(acc[2] + b0.z, 0.f);
    acc[3] = fmaxf(acc[3] + b0.w, 0.f);
    acc[4] = fmaxf(acc[4] + b1.x, 0.f);
    acc[5] = fmaxf(acc[5] + b1.y, 0.f);
    acc[6] = fmaxf(acc[6] + b1.z, 0.f);
    acc[7] = fmaxf(acc[7] + b1.w, 0.f);
    *(uint4*)(Yb + (size_t)chunk * cN + (size_t)node * 8 + L * 4) =
        make_uint4(pack_bf16(acc[0], acc[1]), pack_bf16(acc[2], acc[3]),
                   pack_bf16(acc[4], acc[5]), pack_bf16(acc[6], acc[7]));
}

// ------- agg40_chunk: 8-feature chunks of 64-padded bufC; chunks 0..4 active ---
// Layout: X chunk-major [8][N][4 uints] (16B rows). 1 thread/node, 256/block.

__global__ __launch_bounds__(256) void agg40_chunk(const unsigned* __restrict__ X,
                                                   const int* __restrict__ offsets,
                                                   const int* __restrict__ csr_src,
                                                   const float* __restrict__ bias,
                                                   float* __restrict__ Y,
                                                   int n, size_t cN4) {
    const int chunk = blockIdx.x & 7;
    if (chunk >= 5) return;  // features 40..63 are pad
    const int node = (blockIdx.x >> 3) * 256 + threadIdx.x;
    if (node >= n) return;
    const unsigned* Xc = X + (size_t)chunk * cN4;
    const int e0 = offsets[node];
    const int e1 = offsets[node + 1];
    float acc[8] = {0.f, 0.f, 0.f, 0.f, 0.f, 0.f, 0.f, 0.f};
    int e = e0;
    for (; e + 3 < e1; e += 4) {
        int s0 = csr_src[e];
        int s1 = csr_src[e + 1];
        int s2 = csr_src[e + 2];
        int s3 = csr_src[e + 3];
        uint4 v0 = *(const uint4*)(Xc + (size_t)s0 * 4);
        uint4 v1 = *(const uint4*)(Xc + (size_t)s1 * 4);
        uint4 v2 = *(const uint4*)(Xc + (size_t)s2 * 4);
        uint4 v3 = *(const uint4*)(Xc + (size_t)s3 * 4);
        bf16x8_add(acc, v0);
        bf16x8_add(acc, v1);
        bf16x8_add(acc, v2);
        bf16x8_add(acc, v3);
    }
    for (; e < e1; ++e) {
        int s0 = csr_src[e];
        uint4 v0 = *(const uint4*)(Xc + (size_t)s0 * 4);
        bf16x8_add(acc, v0);
    }
    const float* bp = bias + chunk * 8;
    float4 b0 = *(const float4*)bp;
    float4 b1 = *(const float4*)(bp + 4);
    float* yp = Y + (size_t)node * 40 + chunk * 8;
    *(float4*)yp = make_float4(acc[0] + b0.x, acc[1] + b0.y,
                               acc[2] + b0.z, acc[3] + b0.w);
    *(float4*)(yp + 4) = make_float4(acc[4] + b1.x, acc[5] + b1.y,
                                     acc[6] + b1.z, acc[7] + b1.w);
}

// ------- mm128_mfma: C(chunked bf16) = A @ Wt, MFMA 16x16x32 ----------------
// A: f32 row-major (AF32) or chunked bf16. C: chunked [8][N][8 uints].

template <bool AF32>
__global__ __launch_bounds__(256) void mm128_mfma(const void* __restrict__ Av,
                                                  const unsigned* __restrict__ Wt,
                                                  unsigned* __restrict__ C,
                                                  int n, size_t cN) {
    __shared__ __align__(16) unsigned char smem[128 * 272];  // W then C bounce
    const int t = threadIdx.x;
    const int w = t >> 6;
    const int l = t & 63;
    const int rl = l & 15;
    const int g = l >> 4;
    const int row0 = blockIdx.x * 128;

    for (int i = t; i < 2048; i += 256) {
        int nn = i >> 4, j = i & 15;
        *(uint4*)(smem + nn * 272 + j * 16) = *(const uint4*)(Wt + nn * 64 + j * 4);
    }

    bf16x8_t a[2][4];
#pragma unroll
    for (int rt = 0; rt < 2; ++rt) {
        const int row = row0 + w * 32 + rt * 16 + rl;
        const bool ok = row < n;
#pragma unroll
        for (int kc = 0; kc < 4; ++kc) {
            union { uint4 u; bf16x8_t h; } pk;
            pk.u = make_uint4(0, 0, 0, 0);
            if (AF32) {
                if (ok) {
                    const float* ap = (const float*)Av + (size_t)row * 128 + kc * 32 + g * 8;
                    float4 lo = *(const float4*)ap;
                    float4 hi = *(const float4*)(ap + 4);
                    pk.u = make_uint4(pack_bf16(lo.x, lo.y), pack_bf16(lo.z, lo.w),
                                      pack_bf16(hi.x, hi.y), pack_bf16(hi.z, hi.w));
                }
            } else {
                if (ok)
                    pk.u = *(const uint4*)((const unsigned*)Av +
                                           (size_t)(kc * 2 + (g >> 1)) * cN +
                                           (size_t)row * 8 + (g & 1) * 4);
            }
            a[rt][kc] = pk.h;
        }
    }
    __syncthreads();

    f32x4_t acc[2][8];
#pragma unroll
    for (int rt = 0; rt < 2; ++rt)
#pragma unroll
        for (int ct = 0; ct < 8; ++ct)
            acc[rt][ct] = (f32x4_t){0.f, 0.f, 0.f, 0.f};

#pragma unroll
    for (int ct = 0; ct < 8; ++ct) {
#pragma unroll
        for (int kc = 0; kc < 4; ++kc) {
            bf16x8_t b = *(const bf16x8_t*)(smem + (ct * 16 + rl) * 272 + kc * 64 + g * 16);
            acc[0][ct] = __builtin_amdgcn_mfma_f32_16x16x32_bf16(a[0][kc], b, acc[0][ct], 0, 0, 0);
            acc[1][ct] = __builtin_amdgcn_mfma_f32_16x16x32_bf16(a[1][kc], b, acc[1][ct], 0, 0, 0);
        }
    }
    __syncthreads();

#pragma unroll
    for (int rt = 0; rt < 2; ++rt)
#pragma unroll
        for (int ct = 0; ct < 8; ++ct)
#pragma unroll
            for (int r = 0; r < 4; ++r) {
                int lr = w * 32 + rt * 16 + g * 4 + r;
                int col = ct * 16 + rl;
                *(unsigned short*)(smem + lr * 272 + col * 2) = f2bf(acc[rt][ct][r]);
            }
    __syncthreads();

    for (int i = t; i < 2048; i += 256) {
        int r = i >> 4, j = i & 15;
        int row = row0 + r;
        if (row < n)
            *(uint4*)(C + (size_t)(j >> 1) * cN + (size_t)row * 8 + (j & 1) * 4) =
                *(const uint4*)(smem + r * 272 + j * 16);
    }
}

// ------- mm40_mfma: C(64-pad chunked bf16) = A(chunked) @ W2t[48][128] -------

__global__ __launch_bounds__(256) void mm40_mfma(const unsigned* __restrict__ Ab,
                                                 const unsigned* __restrict__ W2t,
                                                 unsigned* __restrict__ C,
                                                 int n, size_t cN, size_t cN4) {
    __shared__ __align__(16) unsigned char Wlds[48 * 272];   // 13 KB
    __shared__ __align__(16) float bounce[64 * 52];          // 13.3 KB
    const int t = threadIdx.x;
    const int w = t >> 6;
    const int l = t & 63;
    const int rl = l & 15;
    const int g = l >> 4;
    const int row0 = blockIdx.x * 64;

    for (int i = t; i < 768; i += 256) {
        int nn = i >> 4, j = i & 15;
        *(uint4*)(Wlds + nn * 272 + j * 16) = *(const uint4*)(W2t + nn * 64 + j * 4);
    }

    bf16x8_t a[4];
    {
        const int row = row0 + w * 16 + rl;
        const bool ok = row < n;
#pragma unroll
        for (int kc = 0; kc < 4; ++kc) {
            union { uint4 u; bf16x8_t h; } pk;
            pk.u = make_uint4(0, 0, 0, 0);
            if (ok)
                pk.u = *(const uint4*)(Ab + (size_t)(kc * 2 + (g >> 1)) * cN +
                                       (size_t)row * 8 + (g & 1) * 4);
            a[kc] = pk.h;
        }
    }
    __syncthreads();

    f32x4_t acc[3];
#pragma unroll
    for (int ct = 0; ct < 3; ++ct) acc[ct] = (f32x4_t){0.f, 0.f, 0.f, 0.f};

#pragma unroll
    for (int kc = 0; kc < 4; ++kc) {
#pragma unroll
        for (int ct = 0; ct < 3; ++ct) {
            bf16x8_t b = *(const bf16x8_t*)(Wlds + (ct * 16 + rl) * 272 + kc * 64 + g * 16);
            acc[ct] = __builtin_amdgcn_mfma_f32_16x16x32_bf16(a[kc], b, acc[ct], 0, 0, 0);
        }
    }

#pragma unroll
    for (int ct = 0; ct < 3; ++ct)
#pragma unroll
        for (int r = 0; r < 4; ++r)
            bounce[(w * 16 + g * 4 + r) * 52 + ct * 16 + rl] = acc[ct][r];
    __syncthreads();

    for (int i = t; i < 1280; i += 256) {  // 64 rows x 20 u32 (features 0..39)
        int r = i / 20, j = i % 20;
        int row = row0 + r;
        if (row < n)
            C[(size_t)(j >> 2) * cN4 + (size_t)row * 4 + (j & 3)] =
                pack_bf16(bounce[r * 52 + j * 2], bounce[r * 52 + j * 2 + 1]);
    }
}

// ---------------- launch ----------------

extern "C" void kernel_launch(void* const* d_in, const int* in_sizes, int n_in,
                              void* d_out, int out_size, void* d_ws, size_t ws_size,
                              hipStream_t stream) {
    const float* features = (const float*)d_in[0];
    const int* src = (const int*)d_in[1];
    const int* dst = (const int*)d_in[2];
    const float* W0 = (const float*)d_in[3];
    const float* b0 = (const float*)d_in[4];
    const float* W1 = (const float*)d_in[5];
    const float* b1 = (const float*)d_in[6];
    const float* W2 = (const float*)d_in[7];
    const float* b2 = (const float*)d_in[8];
    float* out = (float*)d_out;

    const int n_nodes = in_sizes[0] / FEAT;
    const int n_edges = in_sizes[1];
    const int nb = (n_nodes + 255) >> BIN_SHIFT;
    const size_t cN = (size_t)n_nodes * 8;   // uints per 16-feature chunk
    const size_t cN4 = (size_t)n_nodes * 4;  // uints per 8-feature chunk

    char* p = (char*)d_ws;
    auto alloc = [&](size_t bytes) {
        char* q = p;
        p += (bytes + 255) & ~(size_t)255;
        return q;
    };
    unsigned* bufA  = (unsigned*)alloc((size_t)n_nodes * FEAT * 2);  // chunked bf16
    unsigned* bufB  = (unsigned*)alloc((size_t)n_nodes * FEAT * 2);  // chunked bf16
    int* offsets    = (int*)alloc((size_t)(n_nodes + 1) * 4);
    int* csr        = (int*)alloc((size_t)n_edges * 4);
    int* ebuf       = (int*)alloc((size_t)n_edges * 4);
    int* bin_counts = (int*)alloc(MAX_BINS * 4);
    int* bin_offs   = (int*)alloc((MAX_BINS + 1) * 4);
    int* bin_cursor = (int*)alloc(MAX_BINS * 4);
    unsigned short* Wt0 = (unsigned short*)alloc(16384 * 2);
    unsigned short* Wt1 = (unsigned short*)alloc(16384 * 2);
    unsigned short* W2t = (unsigned short*)alloc(48 * 128 * 2);
    unsigned* bufC  = bufA;  // alias: [8][N][4 uints] fits bufA (bufA dead)

    // weight transpose (independent of CSR chain)
    prep_w<<<152, 256, 0, stream>>>(W0, W1, W2, Wt0, Wt1, W2t);

    // CSR build (binned)
    hipMemsetAsync(bin_counts, 0, MAX_BINS * 4, stream);
    bin_count<<<256, 256, 0, stream>>>(dst, bin_counts, n_edges, nb);
    bin_scan<<<1, 512, 0, stream>>>(bin_counts, bin_offs, bin_cursor, offsets,
                                    nb, n_nodes, n_edges);
    bin_scatter<<<(n_edges + SCAT_TILE - 1) / SCAT_TILE, 256, 0, stream>>>(
        src, dst, bin_cursor, ebuf, n_edges, nb);
    csr_build<<<nb, 256, 0, stream>>>(ebuf, bin_offs, offsets, csr, n_nodes);

    const int mmf_grid = (n_nodes + 127) / 128;
    const int mm40_grid = (n_nodes + 63) / 64;
    const int agg_grid = 8 * ((n_nodes + 127) / 128);
    const int agg40_grid = 8 * ((n_nodes + 255) / 256);

    // layer 0
    mm128_mfma<true><<<mmf_grid, 256, 0, stream>>>(features, (const unsigned*)Wt0,
                                                   bufA, n_nodes, cN);
    agg128_chunk<<<agg_grid, 256, 0, stream>>>(bufA, offsets, csr, b0, bufB,
                                               n_nodes, cN);
    // layer 1
    mm128_mfma<false><<<mmf_grid, 256, 0, stream>>>(bufB, (const unsigned*)Wt1,
                                                    bufA, n_nodes, cN);
    agg128_chunk<<<agg_grid, 256, 0, stream>>>(bufA, offsets, csr, b1, bufB,
                                               n_nodes, cN);
    // layer 2: matmul-first (128->40), then aggregate + bias
    mm40_mfma<<<mm40_grid, 256, 0, stream>>>(bufB, (const unsigned*)W2t, bufC,
                                             n_nodes, cN, cN4);
    agg40_chunk<<<agg40_grid, 256, 0, stream>>>(bufC, offsets, csr, b2, out,
                                                n_nodes, cN4);
}

// Round 13
// 254.948 us; speedup vs baseline: 1.4408x; 1.4408x over previous
//
#include <hip/hip_runtime.h>
#include <hip/hip_bf16.h>

// GCN 3-layer. Linearity: segsum(h[src]) @ W == segsum((h@W)[src]).
// R13: revert to R9 structure (best: 253.8us; R10/R11/R12 all regressed).
//      One change: bufC split into C0[N][32]bf16 (64B-aligned rows) +
//      C1[N][8]bf16 (16B rows) -> agg40's gather rows no longer straddle
//      lines (80B@80B-stride touched ~2.25 lines/row; now 1 line + shared
//      C1 lines). Gather math identical -> absmax unchanged.
// Pipeline:
//   prep_w; bin_count -> bin_scan -> bin_scatter -> csr_build
//   bufA = features @ Wt0        (mm128_mfma<f32 A>)
//   bufB = relu(agg(bufA)+b0)    (agg128_bf16)
//   bufA = bufB @ Wt1            (mm128_mfma<bf16 A>)
//   bufB = relu(agg(bufA)+b1)    (agg128_bf16)
//   C0,C1 = bufB @ W2t           (mm40_mfma, split output)
//   out  = agg40(C0,C1) + b2     (agg40_bf16)

#define FEAT 128
#define BIN_SHIFT 8
#define MAX_BINS 512
#define SCAT_TILE 8192

typedef __attribute__((ext_vector_type(8))) short bf16x8_t;
typedef __attribute__((ext_vector_type(4))) float f32x4_t;

// ---------------- helpers ----------------

__device__ __forceinline__ void bf16x8_add(float* a, uint4 v) {
    a[0] += __uint_as_float(v.x << 16);
    a[1] += __uint_as_float(v.x & 0xffff0000u);
    a[2] += __uint_as_float(v.y << 16);
    a[3] += __uint_as_float(v.y & 0xffff0000u);
    a[4] += __uint_as_float(v.z << 16);
    a[5] += __uint_as_float(v.z & 0xffff0000u);
    a[6] += __uint_as_float(v.w << 16);
    a[7] += __uint_as_float(v.w & 0xffff0000u);
}

__device__ __forceinline__ unsigned pack_bf16(float a, float b) {
    union { __hip_bfloat162 h; unsigned u; } c;
    c.h.x = __float2bfloat16(a);
    c.h.y = __float2bfloat16(b);
    return c.u;
}

__device__ __forceinline__ unsigned short f2bf(float x) {
    union { __hip_bfloat16 h; unsigned short s; } c;
    c.h = __float2bfloat16(x);
    return c.s;
}

// ---------------- CSR build ----------------

__global__ __launch_bounds__(256) void bin_count(const int* __restrict__ dst,
                                                 int* __restrict__ bin_counts,
                                                 int n_edges, int nb) {
    __shared__ int hist[MAX_BINS];
    const int t = threadIdx.x;
    for (int i = t; i < nb; i += 256) hist[i] = 0;
    __syncthreads();
    const int n4 = n_edges >> 2;
    for (int i = blockIdx.x * 256 + t; i < n4; i += gridDim.x * 256) {
        int4 d = ((const int4*)dst)[i];
        atomicAdd(&hist[d.x >> BIN_SHIFT], 1);
        atomicAdd(&hist[d.y >> BIN_SHIFT], 1);
        atomicAdd(&hist[d.z >> BIN_SHIFT], 1);
        atomicAdd(&hist[d.w >> BIN_SHIFT], 1);
    }
    if (blockIdx.x == 0 && t < (n_edges & 3))
        atomicAdd(&hist[dst[n4 * 4 + t] >> BIN_SHIFT], 1);
    __syncthreads();
    for (int i = t; i < nb; i += 256) {
        int h = hist[i];
        if (h) atomicAdd(&bin_counts[i], h);
    }
}

__global__ __launch_bounds__(512) void bin_scan(const int* __restrict__ bin_counts,
                                                int* __restrict__ bin_offsets,
                                                int* __restrict__ bin_cursor,
                                                int* __restrict__ offsets,
                                                int nb, int n_nodes, int n_edges) {
    __shared__ int sc[512];
    const int t = threadIdx.x;
    const int v = (t < nb) ? bin_counts[t] : 0;
    sc[t] = v;
    __syncthreads();
    for (int off = 1; off < 512; off <<= 1) {
        int u = (t >= off) ? sc[t - off] : 0;
        __syncthreads();
        sc[t] += u;
        __syncthreads();
    }
    if (t <= nb) {
        int e = (t < nb) ? (sc[t] - v) : n_edges;
        bin_offsets[t] = e;
        if (t < nb) bin_cursor[t] = e;
    }
    if (t == 0) offsets[n_nodes] = n_edges;
}

__global__ __launch_bounds__(256) void bin_scatter(const int* __restrict__ src,
                                                   const int* __restrict__ dst,
                                                   int* __restrict__ bin_cursor,
                                                   int* __restrict__ ebuf,
                                                   int n_edges, int nb) {
    __shared__ int hist[MAX_BINS];
    __shared__ int cur[MAX_BINS];
    const int t = threadIdx.x;
    const int lo = blockIdx.x * SCAT_TILE;
    const int hi = min(lo + SCAT_TILE, n_edges);
    for (int i = t; i < nb; i += 256) hist[i] = 0;
    __syncthreads();
    for (int i = lo + t; i < hi; i += 256) atomicAdd(&hist[dst[i] >> BIN_SHIFT], 1);
    __syncthreads();
    for (int i = t; i < nb; i += 256) {
        int h = hist[i];
        cur[i] = h ? atomicAdd(&bin_cursor[i], h) : 0;
    }
    __syncthreads();
    for (int i = lo + t; i < hi; i += 256) {
        int d = dst[i];
        int b = d >> BIN_SHIFT;
        int pos = atomicAdd(&cur[b], 1);
        ebuf[pos] = ((d & 255) << 24) | src[i];
    }
}

__global__ __launch_bounds__(256) void csr_build(const int* __restrict__ ebuf,
                                                 const int* __restrict__ bin_offsets,
                                                 int* __restrict__ offsets,
                                                 int* __restrict__ csr,
                                                 int n_nodes) {
    __shared__ int cnt[256];
    __shared__ int sc[256];
    __shared__ int cur[256];
    const int b = blockIdx.x;
    const int t = threadIdx.x;
    const int lo = bin_offsets[b];
    const int hi = bin_offsets[b + 1];
    cnt[t] = 0;
    __syncthreads();
    for (int e = lo + t; e < hi; e += 256)
        atomicAdd(&cnt[((unsigned)ebuf[e]) >> 24], 1);
    __syncthreads();
    const int x = cnt[t];
    sc[t] = x;
    __syncthreads();
    for (int off = 1; off < 256; off <<= 1) {
        int u = (t >= off) ? sc[t - off] : 0;
        __syncthreads();
        sc[t] += u;
        __syncthreads();
    }
    const int start = lo + sc[t] - x;
    cur[t] = start;
    const int node = (b << BIN_SHIFT) + t;
    if (node < n_nodes) offsets[node] = start;
    __syncthreads();
    for (int e = lo + t; e < hi; e += 256) {
        int p = ebuf[e];
        int dl = ((unsigned)p) >> 24;
        int pos = atomicAdd(&cur[dl], 1);
        csr[pos] = p & 0x00FFFFFF;
    }
}

// -------- prep_w: Wt0/Wt1[n][k] bf16 from W0/W1[k][n] f32; W2t[48][128] bf16 ----

__global__ __launch_bounds__(256) void prep_w(const float* __restrict__ W0,
                                              const float* __restrict__ W1,
                                              const float* __restrict__ W2,
                                              unsigned short* __restrict__ Wt0,
                                              unsigned short* __restrict__ Wt1,
                                              unsigned short* __restrict__ W2t) {
    int i = blockIdx.x * 256 + threadIdx.x;  // 0..38911
    if (i < 32768) {
        const float* W = (i < 16384) ? W0 : W1;
        unsigned short* Wt = (i < 16384) ? Wt0 : Wt1;
        int ii = i & 16383;
        int k = ii >> 7, nn = ii & 127;
        Wt[nn * 128 + k] = f2bf(W[ii]);
    } else if (i < 32768 + 48 * 128) {
        int ii = i - 32768;
        int nn = ii >> 7, k = ii & 127;
        W2t[ii] = (nn < 40) ? f2bf(W2[k * 40 + nn]) : (unsigned short)0;
    }
}

// ------- agg128_bf16 (R9 exact): 16 lanes/node, 16 nodes/block, unroll-4 -----

__global__ __launch_bounds__(256) void agg128_bf16(const unsigned* __restrict__ X,
                                                   const int* __restrict__ offsets,
                                                   const int* __restrict__ csr_src,
                                                   const float* __restrict__ bias,
                                                   unsigned* __restrict__ Yb, int n) {
    const int t = threadIdx.x;
    const int g = t >> 4;
    const int lane = t & 15;
    const int node = blockIdx.x * 16 + g;
    if (node >= n) return;
    const int e0 = offsets[node];
    const int e1 = offsets[node + 1];
    const int cu = lane * 4;
    float acc[8] = {0.f, 0.f, 0.f, 0.f, 0.f, 0.f, 0.f, 0.f};
    int e = e0;
    for (; e + 3 < e1; e += 4) {
        int s0 = csr_src[e];
        int s1 = csr_src[e + 1];
        int s2 = csr_src[e + 2];
        int s3 = csr_src[e + 3];
        uint4 v0 = *(const uint4*)(X + (size_t)s0 * 64 + cu);
        uint4 v1 = *(const uint4*)(X + (size_t)s1 * 64 + cu);
        uint4 v2 = *(const uint4*)(X + (size_t)s2 * 64 + cu);
        uint4 v3 = *(const uint4*)(X + (size_t)s3 * 64 + cu);
        bf16x8_add(acc, v0);
        bf16x8_add(acc, v1);
        bf16x8_add(acc, v2);
        bf16x8_add(acc, v3);
    }
    for (; e < e1; ++e) {
        int s0 = csr_src[e];
        uint4 v0 = *(const uint4*)(X + (size_t)s0 * 64 + cu);
        bf16x8_add(acc, v0);
    }
    float4 b0 = *(const float4*)(bias + lane * 8);
    float4 b1 = *(const float4*)(bias + lane * 8 + 4);
    acc[0] = fmaxf(acc[0] + b0.x, 0.f);
    acc[1] = fmaxf(acc[1] + b0.y, 0.f);
    acc[2] = fmaxf(acc[2] + b0.z, 0.f);
    acc[3] = fmaxf(acc[3] + b0.w, 0.f);
    acc[4] = fmaxf(acc[4] + b1.x, 0.f);
    acc[5] = fmaxf(acc[5] + b1.y, 0.f);
    acc[6] = fmaxf(acc[6] + b1.z, 0.f);
    acc[7] = fmaxf(acc[7] + b1.w, 0.f);
    *(uint4*)(Yb + (size_t)node * 64 + cu) =
        make_uint4(pack_bf16(acc[0], acc[1]), pack_bf16(acc[2], acc[3]),
                   pack_bf16(acc[4], acc[5]), pack_bf16(acc[6], acc[7]));
}

// ------- agg40_bf16: out[n,40](f32) = sum over edges of split C0/C1 + bias ---
// C0[N][32]bf16 (64B-aligned rows), C1[N][8]bf16 (16B rows). 8 lanes/node:
// lanes 0..3 read C0 (uint4 each), lane 4 reads C1. 32 nodes/block.

__global__ __launch_bounds__(256) void agg40_bf16(const unsigned* __restrict__ C0,
                                                  const unsigned* __restrict__ C1,
                                                  const int* __restrict__ offsets,
                                                  const int* __restrict__ csr_src,
                                                  const float* __restrict__ bias,
                                                  float* __restrict__ Y, int n) {
    const int t = threadIdx.x;
    const int g = t >> 3;
    const int lane = t & 7;
    const int node = blockIdx.x * 32 + g;
    if (node >= n) return;
    const int e0 = offsets[node];
    const int e1 = offsets[node + 1];
    const bool active = lane < 5;
    const bool inC0 = lane < 4;
    const int cu = lane * 4;  // uint offset in C0 row (lane<4)
    float acc[8] = {0.f, 0.f, 0.f, 0.f, 0.f, 0.f, 0.f, 0.f};
    int e = e0;
    for (; e + 3 < e1; e += 4) {
        int s0 = csr_src[e];
        int s1 = csr_src[e + 1];
        int s2 = csr_src[e + 2];
        int s3 = csr_src[e + 3];
        if (active) {
            uint4 v0, v1, v2, v3;
            if (inC0) {
                v0 = *(const uint4*)(C0 + (size_t)s0 * 16 + cu);
                v1 = *(const uint4*)(C0 + (size_t)s1 * 16 + cu);
                v2 = *(const uint4*)(C0 + (size_t)s2 * 16 + cu);
                v3 = *(const uint4*)(C0 + (size_t)s3 * 16 + cu);
            } else {
                v0 = *(const uint4*)(C1 + (size_t)s0 * 4);
                v1 = *(const uint4*)(C1 + (size_t)s1 * 4);
                v2 = *(const uint4*)(C1 + (size_t)s2 * 4);
                v3 = *(const uint4*)(C1 + (size_t)s3 * 4);
            }
            bf16x8_add(acc, v0);
            bf16x8_add(acc, v1);
            bf16x8_add(acc, v2);
            bf16x8_add(acc, v3);
        }
    }
    for (; e < e1; ++e) {
        int s0 = csr_src[e];
        if (active) {
            uint4 v0 = inC0 ? *(const uint4*)(C0 + (size_t)s0 * 16 + cu)
                            : *(const uint4*)(C1 + (size_t)s0 * 4);
            bf16x8_add(acc, v0);
        }
    }
    if (active) {
        float4 b0 = *(const float4*)(bias + lane * 8);
        float4 b1 = *(const float4*)(bias + lane * 8 + 4);
        float* yp = Y + (size_t)node * 40 + lane * 8;
        *(float4*)yp = make_float4(acc[0] + b0.x, acc[1] + b0.y,
                                   acc[2] + b0.z, acc[3] + b0.w);
        *(float4*)(yp + 4) = make_float4(acc[4] + b1.x, acc[5] + b1.y,
                                         acc[6] + b1.z, acc[7] + b1.w);
    }
}

// ------- mm128_mfma: C[N,128](bf16) = A[N,128] @ Wt, MFMA 16x16x32 ----------

template <bool AF32>
__global__ __launch_bounds__(256) void mm128_mfma(const void* __restrict__ Av,
                                                  const unsigned* __restrict__ Wt,
                                                  unsigned* __restrict__ C, int n) {
    __shared__ __align__(16) unsigned char smem[128 * 272];  // W then C bounce
    const int t = threadIdx.x;
    const int w = t >> 6;
    const int l = t & 63;
    const int rl = l & 15;
    const int g = l >> 4;
    const int row0 = blockIdx.x * 128;

    for (int i = t; i < 2048; i += 256) {
        int nn = i >> 4, j = i & 15;
        *(uint4*)(smem + nn * 272 + j * 16) = *(const uint4*)(Wt + nn * 64 + j * 4);
    }

    bf16x8_t a[2][4];
#pragma unroll
    for (int rt = 0; rt < 2; ++rt) {
        const int row = row0 + w * 32 + rt * 16 + rl;
        const bool ok = row < n;
#pragma unroll
        for (int kc = 0; kc < 4; ++kc) {
            union { uint4 u; bf16x8_t h; } pk;
            pk.u = make_uint4(0, 0, 0, 0);
            if (AF32) {
                if (ok) {
                    const float* ap = (const float*)Av + (size_t)row * 128 + kc * 32 + g * 8;
                    float4 lo = *(const float4*)ap;
                    float4 hi = *(const float4*)(ap + 4);
                    pk.u = make_uint4(pack_bf16(lo.x, lo.y), pack_bf16(lo.z, lo.w),
                                      pack_bf16(hi.x, hi.y), pack_bf16(hi.z, hi.w));
                }
            } else {
                if (ok)
                    pk.u = *(const uint4*)((const unsigned*)Av + (size_t)row * 64 + kc * 16 + g * 4);
            }
            a[rt][kc] = pk.h;
        }
    }
    __syncthreads();

    f32x4_t acc[2][8];
#pragma unroll
    for (int rt = 0; rt < 2; ++rt)
#pragma unroll
        for (int ct = 0; ct < 8; ++ct)
            acc[rt][ct] = (f32x4_t){0.f, 0.f, 0.f, 0.f};

#pragma unroll
    for (int ct = 0; ct < 8; ++ct) {
#pragma unroll
        for (int kc = 0; kc < 4; ++kc) {
            bf16x8_t b = *(const bf16x8_t*)(smem + (ct * 16 + rl) * 272 + kc * 64 + g * 16);
            acc[0][ct] = __builtin_amdgcn_mfma_f32_16x16x32_bf16(a[0][kc], b, acc[0][ct], 0, 0, 0);
            acc[1][ct] = __builtin_amdgcn_mfma_f32_16x16x32_bf16(a[1][kc], b, acc[1][ct], 0, 0, 0);
        }
    }
    __syncthreads();

#pragma unroll
    for (int rt = 0; rt < 2; ++rt)
#pragma unroll
        for (int ct = 0; ct < 8; ++ct)
#pragma unroll
            for (int r = 0; r < 4; ++r) {
                int lr = w * 32 + rt * 16 + g * 4 + r;
                int col = ct * 16 + rl;
                *(unsigned short*)(smem + lr * 272 + col * 2) = f2bf(acc[rt][ct][r]);
            }
    __syncthreads();

    for (int i = t; i < 2048; i += 256) {
        int r = i >> 4, j = i & 15;
        int row = row0 + r;
        if (row < n)
            *(uint4*)(C + (size_t)row * 64 + j * 4) = *(const uint4*)(smem + r * 272 + j * 16);
    }
}

// ------- mm40_mfma: (C0,C1) = A[N,128](bf16) @ W2t[48][128], MFMA ------------
// C0[N][32]bf16 aligned rows (features 0..31), C1[N][8]bf16 (features 32..39).

__global__ __launch_bounds__(256) void mm40_mfma(const unsigned* __restrict__ Ab,
                                                 const unsigned* __restrict__ W2t,
                                                 unsigned* __restrict__ C0,
                                                 unsigned* __restrict__ C1, int n) {
    __shared__ __align__(16) unsigned char Wlds[48 * 272];   // 13 KB
    __shared__ __align__(16) float bounce[64 * 52];          // 13.3 KB
    const int t = threadIdx.x;
    const int w = t >> 6;
    const int l = t & 63;
    const int rl = l & 15;
    const int g = l >> 4;
    const int row0 = blockIdx.x * 64;

    for (int i = t; i < 768; i += 256) {
        int nn = i >> 4, j = i & 15;
        *(uint4*)(Wlds + nn * 272 + j * 16) = *(const uint4*)(W2t + nn * 64 + j * 4);
    }

    bf16x8_t a[4];
    {
        const int row = row0 + w * 16 + rl;
        const bool ok = row < n;
#pragma unroll
        for (int kc = 0; kc < 4; ++kc) {
            union { uint4 u; bf16x8_t h; } pk;
            pk.u = make_uint4(0, 0, 0, 0);
            if (ok)
                pk.u = *(const uint4*)(Ab + (size_t)row * 64 + kc * 16 + g * 4);
            a[kc] = pk.h;
        }
    }
    __syncthreads();

    f32x4_t acc[3];
#pragma unroll
    for (int ct = 0; ct < 3; ++ct) acc[ct] = (f32x4_t){0.f, 0.f, 0.f, 0.f};

#pragma unroll
    for (int kc = 0; kc < 4; ++kc) {
#pragma unroll
        for (int ct = 0; ct < 3; ++ct) {
            bf16x8_t b = *(const bf16x8_t*)(Wlds + (ct * 16 + rl) * 272 + kc * 64 + g * 16);
            acc[ct] = __builtin_amdgcn_mfma_f32_16x16x32_bf16(a[kc], b, acc[ct], 0, 0, 0);
        }
    }

#pragma unroll
    for (int ct = 0; ct < 3; ++ct)
#pragma unroll
        for (int r = 0; r < 4; ++r)
            bounce[(w * 16 + g * 4 + r) * 52 + ct * 16 + rl] = acc[ct][r];
    __syncthreads();

    for (int i = t; i < 1280; i += 256) {  // 64 rows x 20 packed u32
        int r = i / 20, j = i % 20;
        int row = row0 + r;
        if (row >= n) continue;
        unsigned v = pack_bf16(bounce[r * 52 + j * 2], bounce[r * 52 + j * 2 + 1]);
        if (j < 16) C0[(size_t)row * 16 + j] = v;          // features 0..31
        else        C1[(size_t)row * 4 + (j - 16)] = v;    // features 32..39
    }
}

// ---------------- launch ----------------

extern "C" void kernel_launch(void* const* d_in, const int* in_sizes, int n_in,
                              void* d_out, int out_size, void* d_ws, size_t ws_size,
                              hipStream_t stream) {
    const float* features = (const float*)d_in[0];
    const int* src = (const int*)d_in[1];
    const int* dst = (const int*)d_in[2];
    const float* W0 = (const float*)d_in[3];
    const float* b0 = (const float*)d_in[4];
    const float* W1 = (const float*)d_in[5];
    const float* b1 = (const float*)d_in[6];
    const float* W2 = (const float*)d_in[7];
    const float* b2 = (const float*)d_in[8];
    float* out = (float*)d_out;

    const int n_nodes = in_sizes[0] / FEAT;
    const int n_edges = in_sizes[1];
    const int nb = (n_nodes + 255) >> BIN_SHIFT;

    char* p = (char*)d_ws;
    auto alloc = [&](size_t bytes) {
        char* q = p;
        p += (bytes + 255) & ~(size_t)255;
        return q;
    };
    unsigned* bufA  = (unsigned*)alloc((size_t)n_nodes * FEAT * 2);  // bf16 [N,128]
    unsigned* bufB  = (unsigned*)alloc((size_t)n_nodes * FEAT * 2);  // bf16 [N,128]
    int* offsets    = (int*)alloc((size_t)(n_nodes + 1) * 4);
    int* csr        = (int*)alloc((size_t)n_edges * 4);
    int* ebuf       = (int*)alloc((size_t)n_edges * 4);
    int* bin_counts = (int*)alloc(MAX_BINS * 4);
    int* bin_offs   = (int*)alloc((MAX_BINS + 1) * 4);
    int* bin_cursor = (int*)alloc(MAX_BINS * 4);
    unsigned short* Wt0 = (unsigned short*)alloc(16384 * 2);
    unsigned short* Wt1 = (unsigned short*)alloc(16384 * 2);
    unsigned short* W2t = (unsigned short*)alloc(48 * 128 * 2);
    // split bufC aliases bufA ([N,64B] + [N,16B] <= [N,256B]; bufA dead then)
    unsigned* bufC0 = bufA;                                   // [N][16 uints]
    unsigned* bufC1 = bufA + (size_t)n_nodes * 16;            // [N][4 uints]

    // weight transpose (independent of CSR chain)
    prep_w<<<152, 256, 0, stream>>>(W0, W1, W2, Wt0, Wt1, W2t);

    // CSR build (binned)
    hipMemsetAsync(bin_counts, 0, MAX_BINS * 4, stream);
    bin_count<<<256, 256, 0, stream>>>(dst, bin_counts, n_edges, nb);
    bin_scan<<<1, 512, 0, stream>>>(bin_counts, bin_offs, bin_cursor, offsets,
                                    nb, n_nodes, n_edges);
    bin_scatter<<<(n_edges + SCAT_TILE - 1) / SCAT_TILE, 256, 0, stream>>>(
        src, dst, bin_cursor, ebuf, n_edges, nb);
    csr_build<<<nb, 256, 0, stream>>>(ebuf, bin_offs, offsets, csr, n_nodes);

    const int mmf_grid = (n_nodes + 127) / 128;
    const int mm40_grid = (n_nodes + 63) / 64;
    const int agg_grid = (n_nodes + 15) / 16;
    const int agg40_grid = (n_nodes + 31) / 32;

    // layer 0
    mm128_mfma<true><<<mmf_grid, 256, 0, stream>>>(features, (const unsigned*)Wt0, bufA, n_nodes);
    agg128_bf16<<<agg_grid, 256, 0, stream>>>(bufA, offsets, csr, b0, bufB, n_nodes);
    // layer 1
    mm128_mfma<false><<<mmf_grid, 256, 0, stream>>>(bufB, (const unsigned*)Wt1, bufA, n_nodes);
    agg128_bf16<<<agg_grid, 256, 0, stream>>>(bufA, offsets, csr, b1, bufB, n_nodes);
    // layer 2: matmul-first (128->40, split output), then aggregate + bias
    mm40_mfma<<<mm40_grid, 256, 0, stream>>>(bufB, (const unsigned*)W2t, bufC0, bufC1, n_nodes);
    agg40_bf16<<<agg40_grid, 256, 0, stream>>>(bufC0, bufC1, offsets, csr, b2, out, n_nodes);
}

// Round 14
// 252.171 us; speedup vs baseline: 1.4566x; 1.0110x over previous
//
#include <hip/hip_runtime.h>
#include <hip/hip_bf16.h>

// GCN 3-layer. Linearity: segsum(h[src]) @ W == segsum((h@W)[src]).
// R14: dispatch-chain consolidation on the R13 base (compute kernels
//      byte-identical). bin_scan kernel ELIMINATED: bin_scatter and
//      csr_build each redundantly compute the 512-wide bin-offset scan in
//      LDS (<1us/block); scatter reserves ebuf ranges via atomicAdd on a
//      zeroed relative cursor + locally computed bin offset (positions
//      identical to R13). prep_w merged into bin_count's grid (+152
//      blocks, disjoint work). 12 -> 10 dispatches.
// Pipeline:
//   memset(4KB); bin_count_prep -> bin_scatter -> csr_build
//   bufA = features @ Wt0        (mm128_mfma<f32 A>)
//   bufB = relu(agg(bufA)+b0)    (agg128_bf16)
//   bufA = bufB @ Wt1            (mm128_mfma<bf16 A>)
//   bufB = relu(agg(bufA)+b1)    (agg128_bf16)
//   C0,C1 = bufB @ W2t           (mm40_mfma, split output)
//   out  = agg40(C0,C1) + b2     (agg40_bf16)

#define FEAT 128
#define BIN_SHIFT 8
#define MAX_BINS 512
#define SCAT_TILE 8192
#define COUNT_BLOCKS 256
#define PREP_BLOCKS 152

typedef __attribute__((ext_vector_type(8))) short bf16x8_t;
typedef __attribute__((ext_vector_type(4))) float f32x4_t;

// ---------------- helpers ----------------

__device__ __forceinline__ void bf16x8_add(float* a, uint4 v) {
    a[0] += __uint_as_float(v.x << 16);
    a[1] += __uint_as_float(v.x & 0xffff0000u);
    a[2] += __uint_as_float(v.y << 16);
    a[3] += __uint_as_float(v.y & 0xffff0000u);
    a[4] += __uint_as_float(v.z << 16);
    a[5] += __uint_as_float(v.z & 0xffff0000u);
    a[6] += __uint_as_float(v.w << 16);
    a[7] += __uint_as_float(v.w & 0xffff0000u);
}

__device__ __forceinline__ unsigned pack_bf16(float a, float b) {
    union { __hip_bfloat162 h; unsigned u; } c;
    c.h.x = __float2bfloat16(a);
    c.h.y = __float2bfloat16(b);
    return c.u;
}

__device__ __forceinline__ unsigned short f2bf(float x) {
    union { __hip_bfloat16 h; unsigned short s; } c;
    c.h = __float2bfloat16(x);
    return c.s;
}

// ---------------- CSR build ----------------

// blocks [0,256): dst histogram into 256-node bins.
// blocks [256,408): weight transpose (Wt0/Wt1[n][k] bf16; W2t[48][128] bf16).

__global__ __launch_bounds__(256) void bin_count_prep(const int* __restrict__ dst,
                                                      int* __restrict__ bin_counts,
                                                      int n_edges, int nb,
                                                      const float* __restrict__ W0,
                                                      const float* __restrict__ W1,
                                                      const float* __restrict__ W2,
                                                      unsigned short* __restrict__ Wt0,
                                                      unsigned short* __restrict__ Wt1,
                                                      unsigned short* __restrict__ W2t) {
    __shared__ int hist[MAX_BINS];
    const int t = threadIdx.x;

    if (blockIdx.x >= COUNT_BLOCKS) {
        int i = (blockIdx.x - COUNT_BLOCKS) * 256 + t;  // 0..38911
        if (i < 32768) {
            const float* W = (i < 16384) ? W0 : W1;
            unsigned short* Wt = (i < 16384) ? Wt0 : Wt1;
            int ii = i & 16383;
            int k = ii >> 7, nn = ii & 127;
            Wt[nn * 128 + k] = f2bf(W[ii]);
        } else if (i < 32768 + 48 * 128) {
            int ii = i - 32768;
            int nn = ii >> 7, k = ii & 127;
            W2t[ii] = (nn < 40) ? f2bf(W2[k * 40 + nn]) : (unsigned short)0;
        }
        return;
    }

    for (int i = t; i < nb; i += 256) hist[i] = 0;
    __syncthreads();
    const int n4 = n_edges >> 2;
    for (int i = blockIdx.x * 256 + t; i < n4; i += COUNT_BLOCKS * 256) {
        int4 d = ((const int4*)dst)[i];
        atomicAdd(&hist[d.x >> BIN_SHIFT], 1);
        atomicAdd(&hist[d.y >> BIN_SHIFT], 1);
        atomicAdd(&hist[d.z >> BIN_SHIFT], 1);
        atomicAdd(&hist[d.w >> BIN_SHIFT], 1);
    }
    if (blockIdx.x == 0 && t < (n_edges & 3))
        atomicAdd(&hist[dst[n4 * 4 + t] >> BIN_SHIFT], 1);
    __syncthreads();
    for (int i = t; i < nb; i += 256) {
        int h = hist[i];
        if (h) atomicAdd(&bin_counts[i], h);
    }
}

// bin_scatter: per-tile LDS hist + IN-BLOCK redundant bin-offset scan; range
// reservation = local bin offset + atomicAdd on zeroed relative cursor grel.

__global__ __launch_bounds__(256) void bin_scatter(const int* __restrict__ src,
                                                   const int* __restrict__ dst,
                                                   const int* __restrict__ bin_counts,
                                                   int* __restrict__ grel,
                                                   int* __restrict__ ebuf,
                                                   int n_edges, int nb) {
    __shared__ int hist[MAX_BINS];
    __shared__ int cur[MAX_BINS];
    __shared__ int sc[MAX_BINS];
    __shared__ int cnt_l[MAX_BINS];
    const int t = threadIdx.x;
    const int i0 = t, i1 = t + 256;
    const int lo = blockIdx.x * SCAT_TILE;
    const int hi = min(lo + SCAT_TILE, n_edges);

    {
        int c0 = (i0 < nb) ? bin_counts[i0] : 0;
        int c1 = (i1 < nb) ? bin_counts[i1] : 0;
        sc[i0] = c0; cnt_l[i0] = c0; hist[i0] = 0;
        sc[i1] = c1; cnt_l[i1] = c1; hist[i1] = 0;
    }
    __syncthreads();

    for (int i = lo + t; i < hi; i += 256) atomicAdd(&hist[dst[i] >> BIN_SHIFT], 1);

    // inclusive scan over sc[0..511] with 256 threads (Hillis-Steele)
    for (int off = 1; off < MAX_BINS; off <<= 1) {
        int v0 = (i0 >= off) ? sc[i0 - off] : 0;
        int v1 = (i1 >= off) ? sc[i1 - off] : 0;
        __syncthreads();
        sc[i0] += v0;
        sc[i1] += v1;
        __syncthreads();
    }
    // hist atomics complete (barriers above); reserve ranges
    for (int i = t; i < nb; i += 256) {
        int h = hist[i];
        cur[i] = h ? (sc[i] - cnt_l[i]) + atomicAdd(&grel[i], h) : 0;
    }
    __syncthreads();

    for (int i = lo + t; i < hi; i += 256) {
        int d = dst[i];
        int b = d >> BIN_SHIFT;
        int pos = atomicAdd(&cur[b], 1);
        ebuf[pos] = ((d & 255) << 24) | src[i];
    }
}

// csr_build: in-block redundant bin-offset scan replaces bin_offsets array.

__global__ __launch_bounds__(256) void csr_build(const int* __restrict__ ebuf,
                                                 const int* __restrict__ bin_counts,
                                                 int* __restrict__ offsets,
                                                 int* __restrict__ csr,
                                                 int n_nodes, int nb, int n_edges) {
    __shared__ int bsc[MAX_BINS];
    __shared__ int cnt[256];
    __shared__ int sc[256];
    __shared__ int cur[256];
    const int b = blockIdx.x;
    const int t = threadIdx.x;
    const int i0 = t, i1 = t + 256;

    bsc[i0] = (i0 < nb) ? bin_counts[i0] : 0;
    bsc[i1] = (i1 < nb) ? bin_counts[i1] : 0;
    cnt[t] = 0;
    __syncthreads();
    for (int off = 1; off < MAX_BINS; off <<= 1) {
        int v0 = (i0 >= off) ? bsc[i0 - off] : 0;
        int v1 = (i1 >= off) ? bsc[i1 - off] : 0;
        __syncthreads();
        bsc[i0] += v0;
        bsc[i1] += v1;
        __syncthreads();
    }
    const int hi = bsc[b];
    const int lo = hi - bin_counts[b];
    if (b == 0 && t == 0) offsets[n_nodes] = n_edges;

    for (int e = lo + t; e < hi; e += 256)
        atomicAdd(&cnt[((unsigned)ebuf[e]) >> 24], 1);
    __syncthreads();
    const int x = cnt[t];
    sc[t] = x;
    __syncthreads();
    for (int off = 1; off < 256; off <<= 1) {
        int u = (t >= off) ? sc[t - off] : 0;
        __syncthreads();
        sc[t] += u;
        __syncthreads();
    }
    const int start = lo + sc[t] - x;
    cur[t] = start;
    const int node = (b << BIN_SHIFT) + t;
    if (node < n_nodes) offsets[node] = start;
    __syncthreads();
    for (int e = lo + t; e < hi; e += 256) {
        int p = ebuf[e];
        int dl = ((unsigned)p) >> 24;
        int pos = atomicAdd(&cur[dl], 1);
        csr[pos] = p & 0x00FFFFFF;
    }
}

// ------- agg128_bf16 (R9 exact): 16 lanes/node, 16 nodes/block, unroll-4 -----

__global__ __launch_bounds__(256) void agg128_bf16(const unsigned* __restrict__ X,
                                                   const int* __restrict__ offsets,
                                                   const int* __restrict__ csr_src,
                                                   const float* __restrict__ bias,
                                                   unsigned* __restrict__ Yb, int n) {
    const int t = threadIdx.x;
    const int g = t >> 4;
    const int lane = t & 15;
    const int node = blockIdx.x * 16 + g;
    if (node >= n) return;
    const int e0 = offsets[node];
    const int e1 = offsets[node + 1];
    const int cu = lane * 4;
    float acc[8] = {0.f, 0.f, 0.f, 0.f, 0.f, 0.f, 0.f, 0.f};
    int e = e0;
    for (; e + 3 < e1; e += 4) {
        int s0 = csr_src[e];
        int s1 = csr_src[e + 1];
        int s2 = csr_src[e + 2];
        int s3 = csr_src[e + 3];
        uint4 v0 = *(const uint4*)(X + (size_t)s0 * 64 + cu);
        uint4 v1 = *(const uint4*)(X + (size_t)s1 * 64 + cu);
        uint4 v2 = *(const uint4*)(X + (size_t)s2 * 64 + cu);
        uint4 v3 = *(const uint4*)(X + (size_t)s3 * 64 + cu);
        bf16x8_add(acc, v0);
        bf16x8_add(acc, v1);
        bf16x8_add(acc, v2);
        bf16x8_add(acc, v3);
    }
    for (; e < e1; ++e) {
        int s0 = csr_src[e];
        uint4 v0 = *(const uint4*)(X + (size_t)s0 * 64 + cu);
        bf16x8_add(acc, v0);
    }
    float4 b0 = *(const float4*)(bias + lane * 8);
    float4 b1 = *(const float4*)(bias + lane * 8 + 4);
    acc[0] = fmaxf(acc[0] + b0.x, 0.f);
    acc[1] = fmaxf(acc[1] + b0.y, 0.f);
    acc[2] = fmaxf(acc[2] + b0.z, 0.f);
    acc[3] = fmaxf(acc[3] + b0.w, 0.f);
    acc[4] = fmaxf(acc[4] + b1.x, 0.f);
    acc[5] = fmaxf(acc[5] + b1.y, 0.f);
    acc[6] = fmaxf(acc[6] + b1.z, 0.f);
    acc[7] = fmaxf(acc[7] + b1.w, 0.f);
    *(uint4*)(Yb + (size_t)node * 64 + cu) =
        make_uint4(pack_bf16(acc[0], acc[1]), pack_bf16(acc[2], acc[3]),
                   pack_bf16(acc[4], acc[5]), pack_bf16(acc[6], acc[7]));
}

// ------- agg40_bf16 (R13 exact): split C0/C1, 8 lanes/node, 32 nodes/block ---

__global__ __launch_bounds__(256) void agg40_bf16(const unsigned* __restrict__ C0,
                                                  const unsigned* __restrict__ C1,
                                                  const int* __restrict__ offsets,
                                                  const int* __restrict__ csr_src,
                                                  const float* __restrict__ bias,
                                                  float* __restrict__ Y, int n) {
    const int t = threadIdx.x;
    const int g = t >> 3;
    const int lane = t & 7;
    const int node = blockIdx.x * 32 + g;
    if (node >= n) return;
    const int e0 = offsets[node];
    const int e1 = offsets[node + 1];
    const bool active = lane < 5;
    const bool inC0 = lane < 4;
    const int cu = lane * 4;
    float acc[8] = {0.f, 0.f, 0.f, 0.f, 0.f, 0.f, 0.f, 0.f};
    int e = e0;
    for (; e + 3 < e1; e += 4) {
        int s0 = csr_src[e];
        int s1 = csr_src[e + 1];
        int s2 = csr_src[e + 2];
        int s3 = csr_src[e + 3];
        if (active) {
            uint4 v0, v1, v2, v3;
            if (inC0) {
                v0 = *(const uint4*)(C0 + (size_t)s0 * 16 + cu);
                v1 = *(const uint4*)(C0 + (size_t)s1 * 16 + cu);
                v2 = *(const uint4*)(C0 + (size_t)s2 * 16 + cu);
                v3 = *(const uint4*)(C0 + (size_t)s3 * 16 + cu);
            } else {
                v0 = *(const uint4*)(C1 + (size_t)s0 * 4);
                v1 = *(const uint4*)(C1 + (size_t)s1 * 4);
                v2 = *(const uint4*)(C1 + (size_t)s2 * 4);
                v3 = *(const uint4*)(C1 + (size_t)s3 * 4);
            }
            bf16x8_add(acc, v0);
            bf16x8_add(acc, v1);
            bf16x8_add(acc, v2);
            bf16x8_add(acc, v3);
        }
    }
    for (; e < e1; ++e) {
        int s0 = csr_src[e];
        if (active) {
            uint4 v0 = inC0 ? *(const uint4*)(C0 + (size_t)s0 * 16 + cu)
                            : *(const uint4*)(C1 + (size_t)s0 * 4);
            bf16x8_add(acc, v0);
        }
    }
    if (active) {
        float4 b0 = *(const float4*)(bias + lane * 8);
        float4 b1 = *(const float4*)(bias + lane * 8 + 4);
        float* yp = Y + (size_t)node * 40 + lane * 8;
        *(float4*)yp = make_float4(acc[0] + b0.x, acc[1] + b0.y,
                                   acc[2] + b0.z, acc[3] + b0.w);
        *(float4*)(yp + 4) = make_float4(acc[4] + b1.x, acc[5] + b1.y,
                                         acc[6] + b1.z, acc[7] + b1.w);
    }
}

// ------- mm128_mfma: C[N,128](bf16) = A[N,128] @ Wt, MFMA 16x16x32 ----------

template <bool AF32>
__global__ __launch_bounds__(256) void mm128_mfma(const void* __restrict__ Av,
                                                  const unsigned* __restrict__ Wt,
                                                  unsigned* __restrict__ C, int n) {
    __shared__ __align__(16) unsigned char smem[128 * 272];  // W then C bounce
    const int t = threadIdx.x;
    const int w = t >> 6;
    const int l = t & 63;
    const int rl = l & 15;
    const int g = l >> 4;
    const int row0 = blockIdx.x * 128;

    for (int i = t; i < 2048; i += 256) {
        int nn = i >> 4, j = i & 15;
        *(uint4*)(smem + nn * 272 + j * 16) = *(const uint4*)(Wt + nn * 64 + j * 4);
    }

    bf16x8_t a[2][4];
#pragma unroll
    for (int rt = 0; rt < 2; ++rt) {
        const int row = row0 + w * 32 + rt * 16 + rl;
        const bool ok = row < n;
#pragma unroll
        for (int kc = 0; kc < 4; ++kc) {
            union { uint4 u; bf16x8_t h; } pk;
            pk.u = make_uint4(0, 0, 0, 0);
            if (AF32) {
                if (ok) {
                    const float* ap = (const float*)Av + (size_t)row * 128 + kc * 32 + g * 8;
                    float4 lo = *(const float4*)ap;
                    float4 hi = *(const float4*)(ap + 4);
                    pk.u = make_uint4(pack_bf16(lo.x, lo.y), pack_bf16(lo.z, lo.w),
                                      pack_bf16(hi.x, hi.y), pack_bf16(hi.z, hi.w));
                }
            } else {
                if (ok)
                    pk.u = *(const uint4*)((const unsigned*)Av + (size_t)row * 64 + kc * 16 + g * 4);
            }
            a[rt][kc] = pk.h;
        }
    }
    __syncthreads();

    f32x4_t acc[2][8];
#pragma unroll
    for (int rt = 0; rt < 2; ++rt)
#pragma unroll
        for (int ct = 0; ct < 8; ++ct)
            acc[rt][ct] = (f32x4_t){0.f, 0.f, 0.f, 0.f};

#pragma unroll
    for (int ct = 0; ct < 8; ++ct) {
#pragma unroll
        for (int kc = 0; kc < 4; ++kc) {
            bf16x8_t b = *(const bf16x8_t*)(smem + (ct * 16 + rl) * 272 + kc * 64 + g * 16);
            acc[0][ct] = __builtin_amdgcn_mfma_f32_16x16x32_bf16(a[0][kc], b, acc[0][ct], 0, 0, 0);
            acc[1][ct] = __builtin_amdgcn_mfma_f32_16x16x32_bf16(a[1][kc], b, acc[1][ct], 0, 0, 0);
        }
    }
    __syncthreads();

#pragma unroll
    for (int rt = 0; rt < 2; ++rt)
#pragma unroll
        for (int ct = 0; ct < 8; ++ct)
#pragma unroll
            for (int r = 0; r < 4; ++r) {
                int lr = w * 32 + rt * 16 + g * 4 + r;
                int col = ct * 16 + rl;
                *(unsigned short*)(smem + lr * 272 + col * 2) = f2bf(acc[rt][ct][r]);
            }
    __syncthreads();

    for (int i = t; i < 2048; i += 256) {
        int r = i >> 4, j = i & 15;
        int row = row0 + r;
        if (row < n)
            *(uint4*)(C + (size_t)row * 64 + j * 4) = *(const uint4*)(smem + r * 272 + j * 16);
    }
}

// ------- mm40_mfma: (C0,C1) = A[N,128](bf16) @ W2t[48][128], MFMA ------------

__global__ __launch_bounds__(256) void mm40_mfma(const unsigned* __restrict__ Ab,
                                                 const unsigned* __restrict__ W2t,
                                                 unsigned* __restrict__ C0,
                                                 unsigned* __restrict__ C1, int n) {
    __shared__ __align__(16) unsigned char Wlds[48 * 272];   // 13 KB
    __shared__ __align__(16) float bounce[64 * 52];          // 13.3 KB
    const int t = threadIdx.x;
    const int w = t >> 6;
    const int l = t & 63;
    const int rl = l & 15;
    const int g = l >> 4;
    const int row0 = blockIdx.x * 64;

    for (int i = t; i < 768; i += 256) {
        int nn = i >> 4, j = i & 15;
        *(uint4*)(Wlds + nn * 272 + j * 16) = *(const uint4*)(W2t + nn * 64 + j * 4);
    }

    bf16x8_t a[4];
    {
        const int row = row0 + w * 16 + rl;
        const bool ok = row < n;
#pragma unroll
        for (int kc = 0; kc < 4; ++kc) {
            union { uint4 u; bf16x8_t h; } pk;
            pk.u = make_uint4(0, 0, 0, 0);
            if (ok)
                pk.u = *(const uint4*)(Ab + (size_t)row * 64 + kc * 16 + g * 4);
            a[kc] = pk.h;
        }
    }
    __syncthreads();

    f32x4_t acc[3];
#pragma unroll
    for (int ct = 0; ct < 3; ++ct) acc[ct] = (f32x4_t){0.f, 0.f, 0.f, 0.f};

#pragma unroll
    for (int kc = 0; kc < 4; ++kc) {
#pragma unroll
        for (int ct = 0; ct < 3; ++ct) {
            bf16x8_t b = *(const bf16x8_t*)(Wlds + (ct * 16 + rl) * 272 + kc * 64 + g * 16);
            acc[ct] = __builtin_amdgcn_mfma_f32_16x16x32_bf16(a[kc], b, acc[ct], 0, 0, 0);
        }
    }

#pragma unroll
    for (int ct = 0; ct < 3; ++ct)
#pragma unroll
        for (int r = 0; r < 4; ++r)
            bounce[(w * 16 + g * 4 + r) * 52 + ct * 16 + rl] = acc[ct][r];
    __syncthreads();

    for (int i = t; i < 1280; i += 256) {  // 64 rows x 20 packed u32
        int r = i / 20, j = i % 20;
        int row = row0 + r;
        if (row >= n) continue;
        unsigned v = pack_bf16(bounce[r * 52 + j * 2], bounce[r * 52 + j * 2 + 1]);
        if (j < 16) C0[(size_t)row * 16 + j] = v;          // features 0..31
        else        C1[(size_t)row * 4 + (j - 16)] = v;    // features 32..39
    }
}

// ---------------- launch ----------------

extern "C" void kernel_launch(void* const* d_in, const int* in_sizes, int n_in,
                              void* d_out, int out_size, void* d_ws, size_t ws_size,
                              hipStream_t stream) {
    const float* features = (const float*)d_in[0];
    const int* src = (const int*)d_in[1];
    const int* dst = (const int*)d_in[2];
    const float* W0 = (const float*)d_in[3];
    const float* b0 = (const float*)d_in[4];
    const float* W1 = (const float*)d_in[5];
    const float* b1 = (const float*)d_in[6];
    const float* W2 = (const float*)d_in[7];
    const float* b2 = (const float*)d_in[8];
    float* out = (float*)d_out;

    const int n_nodes = in_sizes[0] / FEAT;
    const int n_edges = in_sizes[1];
    const int nb = (n_nodes + 255) >> BIN_SHIFT;

    char* p = (char*)d_ws;
    auto alloc = [&](size_t bytes) {
        char* q = p;
        p += (bytes + 255) & ~(size_t)255;
        return q;
    };
    unsigned* bufA  = (unsigned*)alloc((size_t)n_nodes * FEAT * 2);  // bf16 [N,128]
    unsigned* bufB  = (unsigned*)alloc((size_t)n_nodes * FEAT * 2);  // bf16 [N,128]
    int* offsets    = (int*)alloc((size_t)(n_nodes + 1) * 4);
    int* csr        = (int*)alloc((size_t)n_edges * 4);
    int* ebuf       = (int*)alloc((size_t)n_edges * 4);
    int* bin_counts = (int*)alloc(MAX_BINS * 4);   // 2048B (256-aligned)
    int* grel       = (int*)alloc(MAX_BINS * 4);   // adjacent -> one memset
    unsigned short* Wt0 = (unsigned short*)alloc(16384 * 2);
    unsigned short* Wt1 = (unsigned short*)alloc(16384 * 2);
    unsigned short* W2t = (unsigned short*)alloc(48 * 128 * 2);
    // split bufC aliases bufA ([N,64B] + [N,16B] <= [N,256B]; bufA dead then)
    unsigned* bufC0 = bufA;                                   // [N][16 uints]
    unsigned* bufC1 = bufA + (size_t)n_nodes * 16;            // [N][4 uints]

    // CSR build (binned); weight transpose rides in bin_count_prep's grid
    hipMemsetAsync(bin_counts, 0, MAX_BINS * 4 * 2, stream);  // counts + grel
    bin_count_prep<<<COUNT_BLOCKS + PREP_BLOCKS, 256, 0, stream>>>(
        dst, bin_counts, n_edges, nb, W0, W1, W2, Wt0, Wt1, W2t);
    bin_scatter<<<(n_edges + SCAT_TILE - 1) / SCAT_TILE, 256, 0, stream>>>(
        src, dst, bin_counts, grel, ebuf, n_edges, nb);
    csr_build<<<nb, 256, 0, stream>>>(ebuf, bin_counts, offsets, csr,
                                      n_nodes, nb, n_edges);

    const int mmf_grid = (n_nodes + 127) / 128;
    const int mm40_grid = (n_nodes + 63) / 64;
    const int agg_grid = (n_nodes + 15) / 16;
    const int agg40_grid = (n_nodes + 31) / 32;

    // layer 0
    mm128_mfma<true><<<mmf_grid, 256, 0, stream>>>(features, (const unsigned*)Wt0, bufA, n_nodes);
    agg128_bf16<<<agg_grid, 256, 0, stream>>>(bufA, offsets, csr, b0, bufB, n_nodes);
    // layer 1
    mm128_mfma<false><<<mmf_grid, 256, 0, stream>>>(bufB, (const unsigned*)Wt1, bufA, n_nodes);
    agg128_bf16<<<agg_grid, 256, 0, stream>>>(bufA, offsets, csr, b1, bufB, n_nodes);
    // layer 2: matmul-first (128->40, split output), then aggregate + bias
    mm40_mfma<<<mm40_grid, 256, 0, stream>>>(bufB, (const unsigned*)W2t, bufC0, bufC1, n_nodes);
    agg40_bf16<<<agg40_grid, 256, 0, stream>>>(bufC0, bufC1, offsets, csr, b2, out, n_nodes);
}